// Round 6
// baseline (19591.510 us; speedup 1.0000x reference)
//
#include <hip/hip_runtime.h>

#define Bdim 128
#define Tdim 256
#define Hdim 512
#define INdim 300
#define KXdim 320
#define NC 45
#define NTHR 256

typedef _Float16 h16;
typedef __attribute__((ext_vector_type(8))) _Float16 half8;
typedef __attribute__((ext_vector_type(4))) float float4v;
typedef unsigned long long u64;

// ---------------- prep1: W0 = Wemb @ Wx0 (fp32), cb fused biases ----------------
__global__ __launch_bounds__(NTHR) void prep1_kernel(
    const float* Wemb, const float* bemb,
    const float* Wx_l2r, const float* bx_l2r, const float* bh_l2r,
    const float* Wx_r2l, const float* bx_r2l, const float* bh_r2l,
    float* W0, float* cb)
{
    int gid = blockIdx.x * NTHR + threadIdx.x;
    const int nW0 = 2 * KXdim * Hdim;
    if (gid < nW0) {
        int dir = gid / (KXdim * Hdim);
        int rem = gid % (KXdim * Hdim);
        int i = rem / Hdim, h = rem % Hdim;
        const float* Wx = dir ? Wx_r2l : Wx_l2r;
        float s = 0.f;
        if (i < INdim) {
            for (int k = 0; k < Hdim; ++k)
                s += Wemb[i * Hdim + k] * Wx[k * Hdim + h];
        }
        W0[gid] = s;
    } else {
        int idx = gid - nW0;
        if (idx < 2 * 3 * Hdim) {
            int dir = idx / (3 * Hdim);
            int l = (idx / Hdim) % 3;
            int h = idx % Hdim;
            const float* Wx = dir ? Wx_r2l : Wx_l2r;
            const float* bx = dir ? bx_r2l : bx_l2r;
            const float* bh = dir ? bh_r2l : bh_l2r;
            float s = bx[l * Hdim + h] + bh[l * Hdim + h];
            if (l == 0) {
                for (int k = 0; k < Hdim; ++k)
                    s += bemb[k] * Wx[k * Hdim + h];
            }
            cb[idx] = s;
        }
    }
}

// ---------------- pack_W: fp16 B-frag layout [u][cs16][ks32][nt2][lane64][j8] ----
__global__ __launch_bounds__(NTHR) void pack_W_kernel(
    const float* W0,
    const float* Wx_l2r, const float* Wh_l2r,
    const float* Wx_r2l, const float* Wh_r2l,
    h16* Wfrag)
{
    int e = blockIdx.x * NTHR + threadIdx.x;
    if (e >= 6 * 16 * 32 * 2 * 64 * 8) return;
    int j    = e & 7;
    int lane = (e >> 3) & 63;
    int nt   = (e >> 9) & 1;
    int ks   = (e >> 10) & 31;
    int cs   = (e >> 15) & 15;
    int u    = e >> 19;
    int dir = u / 3, l = u % 3;
    int n  = cs * 32 + nt * 16 + (lane & 15);
    int kk = ks * 32 + ((lane >> 4) * 8) + j;
    float v;
    if (kk < 512) {
        if (l == 0) {
            v = (kk < KXdim) ? W0[(dir * KXdim + kk) * Hdim + n] : 0.f;
        } else {
            const float* Wx = dir ? Wx_r2l : Wx_l2r;
            v = Wx[(l * Hdim + kk) * Hdim + n];
        }
    } else {
        const float* Wh = dir ? Wh_r2l : Wh_l2r;
        v = Wh[(l * Hdim + (kk - 512)) * Hdim + n];
    }
    Wfrag[e] = (h16)v;
}

// ---------------- pack_W0f: fp16 B-frags of W0 for zx0 kernel --------------------
__global__ __launch_bounds__(NTHR) void pack_W0f_kernel(const float* W0, h16* W0f)
{
    int e = blockIdx.x * NTHR + threadIdx.x;
    if (e >= 2 * 32 * 10 * 64 * 8) return;
    int j    = e & 7;
    int lane = (e >> 3) & 63;
    int rest = e >> 9;
    int ks   = rest % 10;
    rest /= 10;
    int nt   = rest & 31;
    int dir  = rest >> 5;
    int k = ks * 32 + ((lane >> 4) * 8) + j;
    int n = nt * 16 + (lane & 15);
    W0f[e] = (h16)W0[(dir * KXdim + k) * Hdim + n];
}

// ---------------- zx0: zx0f[dir][t][nt32][mt8][lane64][reg4] fp16 ----------------
__global__ __launch_bounds__(NTHR) void zx0_kernel(
    const float* __restrict__ x0, const float* __restrict__ x1,
    const h16* __restrict__ W0f, const float* __restrict__ cb,
    h16* __restrict__ zx0f)
{
    int bx = blockIdx.x;
    int t = bx & 255, mh = (bx >> 8) & 1, dir = bx >> 9;
    const int tid = threadIdx.x;
    __shared__ h16 xl[64 * 328];
    const float* xs = dir ? x1 : x0;
    for (int i = tid; i < 64 * 328; i += NTHR) {
        int r = i / 328, k = i - r * 328;
        int b = mh * 64 + r;
        float v = (k < INdim) ? xs[(b * Tdim + t) * INdim + k] : 0.f;
        xl[i] = (h16)v;
    }
    __syncthreads();
    int wave = tid >> 6, lane = tid & 63;
    int r15 = lane & 15, q = lane >> 4;
    for (int nt = 0; nt < 32; ++nt) {
        float4v acc = {0.f, 0.f, 0.f, 0.f};
        #pragma unroll
        for (int ks = 0; ks < 10; ++ks) {
            half8 af = *(const half8*)&xl[(wave * 16 + r15) * 328 + ks * 32 + q * 8];
            half8 bf = *(const half8*)&W0f[(((dir * 32 + nt) * 10 + ks) * 64 + lane) * 8];
            acc = __builtin_amdgcn_mfma_f32_16x16x32_f16(af, bf, acc, 0, 0, 0);
        }
        int col = nt * 16 + r15;
        float cbv = cb[(dir * 3 + 0) * Hdim + col];
        union { h16 h[4]; uint2 u2; } o;
        #pragma unroll
        for (int r = 0; r < 4; ++r) o.h[r] = (h16)(acc[r] + cbv);
        h16* dst = zx0f + (((( (size_t)dir * Tdim + t) * 32 + nt) * 8 + (mh * 4 + wave)) * 64 + lane) * 4;
        *(uint2*)dst = o.u2;
    }
}

// ---------------- main pipeline: batch-parallel, block-LOCAL recurrence ----------
// 16 independent blocks (2 dirs x 8 row-groups of 16 batch rows), 1024 threads
// (16 waves; wave w owns n-tiles {2w, 2w+1}). All 3 layers computed in-block per
// step; h kept in LDS (XOR-swizzled); weights streamed from per-XCD L2.
// NO inter-block communication; plain (non-cooperative) launch.
__global__ __launch_bounds__(1024, 1) void rnn_pipe(
    const h16* __restrict__ Wfrag, const h16* __restrict__ zx0f,
    const float* __restrict__ cb, const float* __restrict__ lng,
    const float* __restrict__ lnb, h16* __restrict__ h2)
{
    const int tid = threadIdx.x;
    const int w = tid >> 6, lane = tid & 63;
    const int r15 = lane & 15, quad = lane >> 4;
    const int blk = blockIdx.x;
    const int dir = (blk >> 2) & 1;                 // blk%8 fixes dir -> one dir per XCD
    const int rg  = (blk & 3) | ((blk >> 3) << 2);  // 0..7 row group (16 rows each)

    __shared__ h16 hb[3][16 * 512];   // h0,h1,h2 tiles; idx = row*512 + (c ^ (row<<3))
    __shared__ float red_s[16][16];
    __shared__ float red_q[16][16];
    __shared__ float mr[16][2];       // rstd, -m*rstd per row

    {   // zero h_prev buffers
        h16* p = &hb[0][0];
        for (int i = tid; i < 3072; i += 1024)
            *(uint4*)(p + i * 8) = make_uint4(0, 0, 0, 0);
    }

    const int ntg0 = w * 2;
    float g2v[3][2], b2v[3][2], cbv[2][2];
    #pragma unroll
    for (int l = 0; l < 3; ++l)
        #pragma unroll
        for (int nt = 0; nt < 2; ++nt) {
            int col = (ntg0 + nt) * 16 + r15;
            g2v[l][nt] = 2.0f * lng[l * Hdim + col];
            b2v[l][nt] = 2.0f * lnb[l * Hdim + col];
        }
    #pragma unroll
    for (int l = 1; l < 3; ++l)
        #pragma unroll
        for (int nt = 0; nt < 2; ++nt) {
            int col = (ntg0 + nt) * 16 + r15;
            cbv[l - 1][nt] = cb[(dir * 3 + l) * Hdim + col];
        }
    const h16* wb[3];
    #pragma unroll
    for (int l = 0; l < 3; ++l)
        wb[l] = Wfrag + (size_t)((dir * 3 + l) * 16 + w) * 32768 + (size_t)lane * 8;
    __syncthreads();

    // stats + tanh + h->LDS for one layer (z held in regs)
    auto finish = [&](float4v ac0, float4v ac1, float gg0, float gg1,
                      float bb0, float bb1, h16* buf) {
        float s[4], q[4];
        #pragma unroll
        for (int r = 0; r < 4; ++r) {
            s[r] = ac0[r] + ac1[r];
            q[r] = __builtin_fmaf(ac0[r], ac0[r], ac1[r] * ac1[r]);
        }
        #pragma unroll
        for (int r = 0; r < 4; ++r) {
            s[r] += __shfl_xor(s[r], 1);  q[r] += __shfl_xor(q[r], 1);
            s[r] += __shfl_xor(s[r], 2);  q[r] += __shfl_xor(q[r], 2);
            s[r] += __shfl_xor(s[r], 4);  q[r] += __shfl_xor(q[r], 4);
            s[r] += __shfl_xor(s[r], 8);  q[r] += __shfl_xor(q[r], 8);
        }
        if (r15 == 0) {
            #pragma unroll
            for (int r = 0; r < 4; ++r) {
                red_s[w][quad * 4 + r] = s[r];
                red_q[w][quad * 4 + r] = q[r];
            }
        }
        __syncthreads();
        if (tid < 16) {
            float ss = 0.f, qq = 0.f;
            #pragma unroll
            for (int ww = 0; ww < 16; ++ww) { ss += red_s[ww][tid]; qq += red_q[ww][tid]; }
            float m = ss * (1.0f / Hdim);
            float var = qq * (1.0f / Hdim) - m * m;
            float rstd = rsqrtf(var + 1e-5f);
            mr[tid][0] = rstd;
            mr[tid][1] = -m * rstd;
        }
        __syncthreads();
        #pragma unroll
        for (int r = 0; r < 4; ++r) {
            int row = quad * 4 + r;
            float A = mr[row][0], C = mr[row][1];
            float x0 = __builtin_fmaf(__builtin_fmaf(ac0[r], A, C), gg0, bb0);
            float x1 = __builtin_fmaf(__builtin_fmaf(ac1[r], A, C), gg1, bb1);
            float E0 = __expf(x0), E1 = __expf(x1);
            int c0 = (ntg0 + 0) * 16 + r15;
            int c1 = (ntg0 + 1) * 16 + r15;
            buf[row * 512 + (c0 ^ (row << 3))] = (h16)(1.0f - __fdividef(2.0f, E0 + 1.0f));
            buf[row * 512 + (c1 ^ (row << 3))] = (h16)(1.0f - __fdividef(2.0f, E1 + 1.0f));
        }
        __syncthreads();
    };

    for (int t = 0; t < Tdim; ++t) {
        // ---------------- layer 0: z0 = zx0(t) + h0_prev @ Wh0 ----------------
        float4v aA0, aA1, aB0, aB1;
        {
            const h16* zp = zx0f + ((((size_t)dir * Tdim + t) * 32 + ntg0) * 8 + rg) * 256 + lane * 4;
            union { uint2 u; h16 h[4]; } v0, v1;
            v0.u = *(const uint2*)zp;
            v1.u = *(const uint2*)(zp + 2048);
            #pragma unroll
            for (int r = 0; r < 4; ++r) { aA0[r] = (float)v0.h[r]; aA1[r] = (float)v1.h[r]; }
            aB0 = (float4v){0.f, 0.f, 0.f, 0.f};
            aB1 = (float4v){0.f, 0.f, 0.f, 0.f};
        }
        #pragma unroll
        for (int kk = 0; kk < 16; ++kk) {
            int c0 = kk * 32 + quad * 8;
            half8 af = *(const half8*)&hb[0][r15 * 512 + (c0 ^ (r15 << 3))];
            half8 bf0 = *(const half8*)&wb[0][(size_t)(16 + kk) * 1024];
            half8 bf1 = *(const half8*)&wb[0][(size_t)(16 + kk) * 1024 + 512];
            if (kk & 1) {
                aB0 = __builtin_amdgcn_mfma_f32_16x16x32_f16(af, bf0, aB0, 0, 0, 0);
                aB1 = __builtin_amdgcn_mfma_f32_16x16x32_f16(af, bf1, aB1, 0, 0, 0);
            } else {
                aA0 = __builtin_amdgcn_mfma_f32_16x16x32_f16(af, bf0, aA0, 0, 0, 0);
                aA1 = __builtin_amdgcn_mfma_f32_16x16x32_f16(af, bf1, aA1, 0, 0, 0);
            }
        }
        finish(aA0 + aB0, aA1 + aB1, g2v[0][0], g2v[0][1], b2v[0][0], b2v[0][1], hb[0]);

        // ---------- layers 1,2: z = h_low @ Wx + h_prev @ Wh + cb ----------
        #pragma unroll
        for (int l = 1; l < 3; ++l) {
            float4v cA0 = {0.f,0.f,0.f,0.f}, cA1 = {0.f,0.f,0.f,0.f};
            float4v cB0 = {0.f,0.f,0.f,0.f}, cB1 = {0.f,0.f,0.f,0.f};
            #pragma unroll
            for (int ks = 0; ks < 32; ++ks) {
                const h16* src = (ks < 16) ? hb[l - 1] : hb[l];
                int c0 = (ks & 15) * 32 + quad * 8;
                half8 af = *(const half8*)&src[r15 * 512 + (c0 ^ (r15 << 3))];
                half8 bf0 = *(const half8*)&wb[l][(size_t)ks * 1024];
                half8 bf1 = *(const half8*)&wb[l][(size_t)ks * 1024 + 512];
                if (ks & 1) {
                    cB0 = __builtin_amdgcn_mfma_f32_16x16x32_f16(af, bf0, cB0, 0, 0, 0);
                    cB1 = __builtin_amdgcn_mfma_f32_16x16x32_f16(af, bf1, cB1, 0, 0, 0);
                } else {
                    cA0 = __builtin_amdgcn_mfma_f32_16x16x32_f16(af, bf0, cA0, 0, 0, 0);
                    cA1 = __builtin_amdgcn_mfma_f32_16x16x32_f16(af, bf1, cA1, 0, 0, 0);
                }
            }
            float4v z0 = cA0 + cB0, z1 = cA1 + cB1;
            #pragma unroll
            for (int r = 0; r < 4; ++r) { z0[r] += cbv[l - 1][0]; z1[r] += cbv[l - 1][1]; }
            finish(z0, z1, g2v[l][0], g2v[l][1], b2v[l][0], b2v[l][1], hb[l]);
            if (l == 2) {
                int row = tid >> 6, ch = tid & 63;
                uint4 v = *(const uint4*)&hb[2][row * 512 + ((ch * 8) ^ (row << 3))];
                *(uint4*)&h2[(((size_t)dir * Tdim + t) * Bdim + rg * 16 + row) * Hdim + ch * 8] = v;
            }
        }
    }
}

// ---------------- FC: logits = [h_l2r ; gather(h_r2l)] @ W_fc + b_fc -------------
__global__ __launch_bounds__(NTHR) void fc_kernel(
    const h16* __restrict__ h2, const int* __restrict__ pad,
    const float* __restrict__ Wfc, const float* __restrict__ bfc,
    float* __restrict__ out)
{
    __shared__ float sA[64 * 68];
    __shared__ float sB[64 * 48];
    const int blk = blockIdx.x, tid = threadIdx.x;
    const int b = blk >> 2;
    const int j0 = (blk & 3) * 64;
    const int p = pad[b];
    const int rg = tid >> 4;
    const int c0 = (tid & 15) * 3;
    float acc[4][3] = {};

    for (int k0 = 0; k0 < 2 * Hdim; k0 += 64) {
        {
            int rr = tid >> 2;
            int kp = (tid & 3) * 16;
            int j = j0 + rr;
            const h16* src;
            if (k0 < Hdim) {
                src = h2 + (((size_t)0 * Tdim + j) * Bdim + b) * Hdim + k0 + kp;
            } else {
                int idx = (j < p) ? (p - j - 1) : j;
                src = h2 + (((size_t)1 * Tdim + idx) * Bdim + b) * Hdim + (k0 - Hdim) + kp;
            }
            union { uint4 u4; h16 h[8]; } w0, w1;
            w0.u4 = *(const uint4*)src;
            w1.u4 = *(const uint4*)(src + 8);
            #pragma unroll
            for (int i = 0; i < 8; ++i) {
                sA[rr * 68 + kp + i]     = (float)w0.h[i];
                sA[rr * 68 + kp + 8 + i] = (float)w1.h[i];
            }
        }
        for (int e = tid; e < 64 * 48; e += NTHR) {
            int kk = e / 48, c = e - kk * 48;
            sB[e] = (c < NC) ? Wfc[(k0 + kk) * NC + c] : 0.f;
        }
        __syncthreads();
        for (int kk = 0; kk < 64; ++kk) {
            float b0 = sB[kk * 48 + c0 + 0];
            float b1 = sB[kk * 48 + c0 + 1];
            float b2 = sB[kk * 48 + c0 + 2];
            #pragma unroll
            for (int i = 0; i < 4; ++i) {
                float av = sA[(rg * 4 + i) * 68 + kk];
                acc[i][0] += av * b0; acc[i][1] += av * b1; acc[i][2] += av * b2;
            }
        }
        __syncthreads();
    }
    #pragma unroll
    for (int i = 0; i < 4; ++i) {
        int r = blk * 64 + rg * 4 + i;
        #pragma unroll
        for (int jj = 0; jj < 3; ++jj) {
            int c = c0 + jj;
            if (c < NC) out[r * NC + c] = acc[i][jj] + bfc[c];
        }
    }
}

extern "C" void kernel_launch(void* const* d_in, const int* in_sizes, int n_in,
                              void* d_out, int out_size, void* d_ws, size_t ws_size,
                              hipStream_t stream) {
    const float* x      = (const float*)d_in[0];
    const float* rx     = (const float*)d_in[1];
    const int*   pad    = (const int*)d_in[2];
    const float* Wemb   = (const float*)d_in[4];
    const float* bemb   = (const float*)d_in[5];
    const float* Wx_l2r = (const float*)d_in[6];
    const float* bx_l2r = (const float*)d_in[7];
    const float* Wh_l2r = (const float*)d_in[8];
    const float* bh_l2r = (const float*)d_in[9];
    const float* Wx_r2l = (const float*)d_in[10];
    const float* bx_r2l = (const float*)d_in[11];
    const float* Wh_r2l = (const float*)d_in[12];
    const float* bh_r2l = (const float*)d_in[13];
    const float* lng    = (const float*)d_in[14];
    const float* lnb    = (const float*)d_in[15];
    const float* Wfc    = (const float*)d_in[16];
    const float* bfc    = (const float*)d_in[17];

    char* base = (char*)d_ws;
    size_t off = 0;
    auto alloc = [&](size_t bytes) { char* p = base + off; off += (bytes + 255) & ~(size_t)255; return p; };
    h16*   zx0f  = (h16*)  alloc((size_t)2 * Tdim * 32 * 8 * 64 * 4 * 2);      // 67 MB
    h16*   h2    = (h16*)  alloc((size_t)2 * Tdim * Bdim * Hdim * 2);          // 67 MB
    h16*   Wfrag = (h16*)  alloc((size_t)6 * 16 * 32768 * 2);                  // 6.3 MB
    h16*   W0f   = (h16*)  alloc((size_t)2 * 32 * 10 * 64 * 8 * 2);            // 0.66 MB
    float* W0    = (float*)alloc((size_t)2 * KXdim * Hdim * 4);
    float* cb    = (float*)alloc((size_t)2 * 3 * Hdim * 4);

    prep1_kernel<<<(2 * KXdim * Hdim + 2 * 3 * Hdim) / NTHR, NTHR, 0, stream>>>(
        Wemb, bemb, Wx_l2r, bx_l2r, bh_l2r, Wx_r2l, bx_r2l, bh_r2l, W0, cb);

    pack_W_kernel<<<(6 * 16 * 32 * 2 * 64 * 8) / NTHR, NTHR, 0, stream>>>(
        W0, Wx_l2r, Wh_l2r, Wx_r2l, Wh_r2l, Wfrag);

    pack_W0f_kernel<<<(2 * 32 * 10 * 64 * 8) / NTHR, NTHR, 0, stream>>>(W0, W0f);

    zx0_kernel<<<1024, NTHR, 0, stream>>>(x, rx, W0f, cb, zx0f);

    rnn_pipe<<<dim3(16), dim3(1024), 0, stream>>>(Wfrag, zx0f, cb, lng, lnb, h2);

    fc_kernel<<<(Bdim * Tdim) / 64, NTHR, 0, stream>>>(h2, pad, Wfc, bfc, (float*)d_out);
}

// Round 7
// 4255.857 us; speedup vs baseline: 4.6034x; 4.6034x over previous
//
#include <hip/hip_runtime.h>

#define Bdim 128
#define Tdim 256
#define Hdim 512
#define INdim 300
#define KXdim 320
#define NC 45
#define NTHR 256
#define FPAD 16   // ints per flag (64B cache line padding)

typedef _Float16 h16;
typedef __attribute__((ext_vector_type(8))) _Float16 half8;
typedef __attribute__((ext_vector_type(4))) float float4v;
typedef unsigned long long u64;

// ---- coherence-point access helpers: agent-scope atomics (R4-proven) ----
__device__ __forceinline__ int ld_flag(const int* p) {
    return __hip_atomic_load((int*)p, __ATOMIC_RELAXED, __HIP_MEMORY_SCOPE_AGENT);
}
__device__ __forceinline__ void st_flag_rel(int* p, int v) {
    __hip_atomic_store(p, v, __ATOMIC_RELEASE, __HIP_MEMORY_SCOPE_AGENT);
}
__device__ __forceinline__ half8 ld16c(const h16* p) {
    union { u64 u[2]; half8 h; } r;
    const u64* q = (const u64*)p;
    r.u[0] = __hip_atomic_load((u64*)(q + 0), __ATOMIC_RELAXED, __HIP_MEMORY_SCOPE_AGENT);
    r.u[1] = __hip_atomic_load((u64*)(q + 1), __ATOMIC_RELAXED, __HIP_MEMORY_SCOPE_AGENT);
    return r.h;
}
__device__ __forceinline__ void st8c(h16* p, const uint* u) {
    uint* q = (uint*)p;
    __hip_atomic_store(q + 0, u[0], __ATOMIC_RELAXED, __HIP_MEMORY_SCOPE_AGENT);
    __hip_atomic_store(q + 1, u[1], __ATOMIC_RELAXED, __HIP_MEMORY_SCOPE_AGENT);
    __hip_atomic_store(q + 2, u[2], __ATOMIC_RELAXED, __HIP_MEMORY_SCOPE_AGENT);
    __hip_atomic_store(q + 3, u[3], __ATOMIC_RELAXED, __HIP_MEMORY_SCOPE_AGENT);
}
__device__ __forceinline__ void st_ps(float* p, float s, float q) {
    union { float f[2]; u64 u; } v; v.f[0] = s; v.f[1] = q;
    __hip_atomic_store((u64*)p, v.u, __ATOMIC_RELAXED, __HIP_MEMORY_SCOPE_AGENT);
}
__device__ __forceinline__ void ld_ps(const float* p, float& s, float& q) {
    union { float f[2]; u64 u; } v;
    v.u = __hip_atomic_load((u64*)p, __ATOMIC_RELAXED, __HIP_MEMORY_SCOPE_AGENT);
    s = v.f[0]; q = v.f[1];
}

// ---------------- prep1: W0 = Wemb @ Wx0 (fp32), cb fused biases ----------------
__global__ __launch_bounds__(NTHR) void prep1_kernel(
    const float* Wemb, const float* bemb,
    const float* Wx_l2r, const float* bx_l2r, const float* bh_l2r,
    const float* Wx_r2l, const float* bx_r2l, const float* bh_r2l,
    float* W0, float* cb)
{
    int gid = blockIdx.x * NTHR + threadIdx.x;
    const int nW0 = 2 * KXdim * Hdim;
    if (gid < nW0) {
        int dir = gid / (KXdim * Hdim);
        int rem = gid % (KXdim * Hdim);
        int i = rem / Hdim, h = rem % Hdim;
        const float* Wx = dir ? Wx_r2l : Wx_l2r;
        float s = 0.f;
        if (i < INdim) {
            for (int k = 0; k < Hdim; ++k)
                s += Wemb[i * Hdim + k] * Wx[k * Hdim + h];
        }
        W0[gid] = s;
    } else {
        int idx = gid - nW0;
        if (idx < 2 * 3 * Hdim) {
            int dir = idx / (3 * Hdim);
            int l = (idx / Hdim) % 3;
            int h = idx % Hdim;
            const float* Wx = dir ? Wx_r2l : Wx_l2r;
            const float* bx = dir ? bx_r2l : bx_l2r;
            const float* bh = dir ? bh_r2l : bh_l2r;
            float s = bx[l * Hdim + h] + bh[l * Hdim + h];
            if (l == 0) {
                for (int k = 0; k < Hdim; ++k)
                    s += bemb[k] * Wx[k * Hdim + h];
            }
            cb[idx] = s;
        }
    }
}

// ---------------- pack_W: fp16 B-frag layout [u][cs16][ks32][nt2][lane64][j8] ----
__global__ __launch_bounds__(NTHR) void pack_W_kernel(
    const float* W0,
    const float* Wx_l2r, const float* Wh_l2r,
    const float* Wx_r2l, const float* Wh_r2l,
    h16* Wfrag)
{
    int e = blockIdx.x * NTHR + threadIdx.x;
    if (e >= 6 * 16 * 32 * 2 * 64 * 8) return;
    int j    = e & 7;
    int lane = (e >> 3) & 63;
    int nt   = (e >> 9) & 1;
    int ks   = (e >> 10) & 31;
    int cs   = (e >> 15) & 15;
    int u    = e >> 19;
    int dir = u / 3, l = u % 3;
    int n  = cs * 32 + nt * 16 + (lane & 15);
    int kk = ks * 32 + ((lane >> 4) * 8) + j;
    float v;
    if (kk < 512) {
        if (l == 0) {
            v = (kk < KXdim) ? W0[(dir * KXdim + kk) * Hdim + n] : 0.f;
        } else {
            const float* Wx = dir ? Wx_r2l : Wx_l2r;
            v = Wx[(l * Hdim + kk) * Hdim + n];
        }
    } else {
        const float* Wh = dir ? Wh_r2l : Wh_l2r;
        v = Wh[(l * Hdim + (kk - 512)) * Hdim + n];
    }
    Wfrag[e] = (h16)v;
}

// ---------------- pack_W0f: fp16 B-frags of W0 for zx0 kernel --------------------
__global__ __launch_bounds__(NTHR) void pack_W0f_kernel(const float* W0, h16* W0f)
{
    int e = blockIdx.x * NTHR + threadIdx.x;
    if (e >= 2 * 32 * 10 * 64 * 8) return;
    int j    = e & 7;
    int lane = (e >> 3) & 63;
    int rest = e >> 9;
    int ks   = rest % 10;
    rest /= 10;
    int nt   = rest & 31;
    int dir  = rest >> 5;
    int k = ks * 32 + ((lane >> 4) * 8) + j;
    int n = nt * 16 + (lane & 15);
    W0f[e] = (h16)W0[(dir * KXdim + k) * Hdim + n];
}

// ---------------- zx0: zx0f[dir][t][nt32][mt8][lane64][reg4] fp16 ----------------
__global__ __launch_bounds__(NTHR) void zx0_kernel(
    const float* __restrict__ x0, const float* __restrict__ x1,
    const h16* __restrict__ W0f, const float* __restrict__ cb,
    h16* __restrict__ zx0f)
{
    int bx = blockIdx.x;
    int t = bx & 255, mh = (bx >> 8) & 1, dir = bx >> 9;
    const int tid = threadIdx.x;
    __shared__ h16 xl[64 * 328];
    const float* xs = dir ? x1 : x0;
    for (int i = tid; i < 64 * 328; i += NTHR) {
        int r = i / 328, k = i - r * 328;
        int b = mh * 64 + r;
        float v = (k < INdim) ? xs[(b * Tdim + t) * INdim + k] : 0.f;
        xl[i] = (h16)v;
    }
    __syncthreads();
    int wave = tid >> 6, lane = tid & 63;
    int r15 = lane & 15, q = lane >> 4;
    for (int nt = 0; nt < 32; ++nt) {
        float4v acc = {0.f, 0.f, 0.f, 0.f};
        #pragma unroll
        for (int ks = 0; ks < 10; ++ks) {
            half8 af = *(const half8*)&xl[(wave * 16 + r15) * 328 + ks * 32 + q * 8];
            half8 bf = *(const half8*)&W0f[(((dir * 32 + nt) * 10 + ks) * 64 + lane) * 8];
            acc = __builtin_amdgcn_mfma_f32_16x16x32_f16(af, bf, acc, 0, 0, 0);
        }
        int col = nt * 16 + r15;
        float cbv = cb[(dir * 3 + 0) * Hdim + col];
        union { h16 h[4]; uint2 u2; } o;
        #pragma unroll
        for (int r = 0; r < 4; ++r) o.h[r] = (h16)(acc[r] + cbv);
        h16* dst = zx0f + (((( (size_t)dir * Tdim + t) * 32 + nt) * 8 + (mh * 4 + wave)) * 64 + lane) * 4;
        *(uint2*)dst = o.u2;
    }
}

// ---------------- zeroinit: flags ------------------------------------------------
__global__ __launch_bounds__(NTHR) void zeroinit_kernel(int* hdone, int* sdone)
{
    int gid = blockIdx.x * NTHR + threadIdx.x;
    if (gid < 192 * FPAD) { hdone[gid] = 0; sdone[gid] = 0; }
}

// ---------------- main persistent pipeline kernel --------------------------------
// 192 blocks = 6 units (dir,layer) x 2 row-halves (64 rows) x 16 col-slices
// (32 cols). Per block: fused [Wx;Wh] 32-col weight slice resident in LDS
// (64 KB, loaded ONCE). Per step: A-frags (h_low(t), h_own(t-1)) batch-loaded
// from LLC; 64 MFMA/wave; partial LN stats (512 B) published under sdone;
// peers' stats summed; tanh applied to OWN 64x32 slice only; h published as
// A-frags under hdone. Two small LLC round-trips/step, zero weight traffic.
struct PipeArgs {
    const h16* Wfrag;    // [6][cs16][ks32][nt2][64][8]
    const h16* zx0f;     // [2][T][nt32][mt8][64][4] fp16
    const float* cb;     // [2][3][H]
    const float* lng;    // [3][H]
    const float* lnb;    // [3][H]
    h16* hbuf;           // [6][slot4][rh2][kf16][mt4][64][8] post-tanh h A-frags
    float* pstat;        // [6][slot4][rh2][cs16][row64][2]  (s, q) pairs
    h16* h2;             // [2][T][B][H]
    int* hdone;          // [6][2][16] * FPAD
    int* sdone;          // [6][2][16] * FPAD
};

__device__ __forceinline__ size_t hb_idx(int u, int slot, int rh, int kf, int mt) {
    return ((((size_t)(u * 4 + slot) * 2 + rh) * 16 + kf) * 4 + mt) * 512;
}

__global__ __launch_bounds__(NTHR, 2) void rnn_pipe(PipeArgs a)
{
    const int blk = blockIdx.x, tid = threadIdx.x;
    const int w = tid >> 6, lane = tid & 63;
    const int r15 = lane & 15, quad = lane >> 4;
    const int u = blk >> 5, rh = (blk >> 4) & 1, cs = blk & 15;
    const int dir = u / 3, l = u % 3;

    __shared__ h16 wlds[32768];      // 64 KB: fused W slice [ks32][nt2][64][8]
    __shared__ h16 tile[4][512];     // 4 KB: per-wave 16x32 transpose tiles
    __shared__ float mr[64][2];      // rstd, -m*rstd per row

    {   // stage weight slice once (straight 64 KB copy of Wfrag[u][cs])
        const h16* wsrc = a.Wfrag + (size_t)(u * 16 + cs) * 32768;
        for (int i = tid * 8; i < 32768; i += NTHR * 8)
            *(uint4*)&wlds[i] = *(const uint4*)&wsrc[i];
    }
    // per-lane LN/bias constants (cols cs*32 + n*16 + r15)
    float g2[2], b2[2], cbv[2];
    #pragma unroll
    for (int n = 0; n < 2; ++n) {
        int col = cs * 32 + n * 16 + r15;
        g2[n] = 2.0f * a.lng[l * Hdim + col];
        b2[n] = 2.0f * a.lnb[l * Hdim + col];
        cbv[n] = (l > 0) ? a.cb[(dir * 3 + l) * Hdim + col] : 0.f;   // l0: baked in zx0f
    }
    __syncthreads();

    const int fl = ((u * 2 + rh) * 16 + cs) * FPAD;
    const int gmt = rh * 4 + w;   // global m-tile for zx0f

    for (int t = 0; t < Tdim; ++t) {
        // ---- wait-1: own peers h(t-1); lower h(t); upper-throttle h(t-4) freed ----
        for (;;) {
            int ok = 1;
            if (tid < 16) {
                if (t > 0) ok = (ld_flag(&a.hdone[((u * 2 + rh) * 16 + tid) * FPAD]) >= t);
            } else if (tid >= 64 && tid < 80) {
                if (l > 0) ok = (ld_flag(&a.hdone[(((u - 1) * 2 + rh) * 16 + (tid - 64)) * FPAD]) >= t + 1);
            } else if (tid >= 128 && tid < 144) {
                if (l < 2 && t >= 4) ok = (ld_flag(&a.hdone[(((u + 1) * 2 + rh) * 16 + (tid - 128)) * FPAD]) >= t - 3);
            }
            if (__syncthreads_and(ok)) break;
            __builtin_amdgcn_s_sleep(1);
        }
        asm volatile("" ::: "memory");

        // ---- accumulator init ----
        float4v acc0, acc1;
        if (l == 0) {
            const h16* zp = a.zx0f +
                ((((size_t)dir * Tdim + t) * 32 + cs * 2) * 8 + gmt) * 256 + lane * 4;
            union { uint2 uu; h16 hh[4]; } v0, v1;
            v0.uu = *(const uint2*)zp;
            v1.uu = *(const uint2*)(zp + 2048);
            #pragma unroll
            for (int r = 0; r < 4; ++r) { acc0[r] = (float)v0.hh[r]; acc1[r] = (float)v1.hh[r]; }
        } else {
            acc0 = (float4v){0.f, 0.f, 0.f, 0.f};
            acc1 = (float4v){0.f, 0.f, 0.f, 0.f};
        }

        // ---- batch A-frag loads (overlapped LLC RTTs), then MFMAs ----
        half8 afL[16], afP[16];
        if (l > 0) {
            const h16* hbL = a.hbuf + hb_idx(u - 1, t & 3, rh, 0, w) + lane * 8;
            #pragma unroll
            for (int ks = 0; ks < 16; ++ks)
                afL[ks] = ld16c(hbL + (size_t)ks * 2048);
        }
        if (t > 0) {
            const h16* hbP = a.hbuf + hb_idx(u, (t + 3) & 3, rh, 0, w) + lane * 8;
            #pragma unroll
            for (int ks = 0; ks < 16; ++ks)
                afP[ks] = ld16c(hbP + (size_t)ks * 2048);
        }
        if (l > 0) {
            #pragma unroll
            for (int ks = 0; ks < 16; ++ks) {
                half8 b0 = *(const half8*)&wlds[((ks * 2 + 0) * 64 + lane) * 8];
                half8 b1 = *(const half8*)&wlds[((ks * 2 + 1) * 64 + lane) * 8];
                acc0 = __builtin_amdgcn_mfma_f32_16x16x32_f16(afL[ks], b0, acc0, 0, 0, 0);
                acc1 = __builtin_amdgcn_mfma_f32_16x16x32_f16(afL[ks], b1, acc1, 0, 0, 0);
            }
        }
        if (t > 0) {
            #pragma unroll
            for (int ks = 0; ks < 16; ++ks) {
                half8 b0 = *(const half8*)&wlds[(((ks + 16) * 2 + 0) * 64 + lane) * 8];
                half8 b1 = *(const half8*)&wlds[(((ks + 16) * 2 + 1) * 64 + lane) * 8];
                acc0 = __builtin_amdgcn_mfma_f32_16x16x32_f16(afP[ks], b0, acc0, 0, 0, 0);
                acc1 = __builtin_amdgcn_mfma_f32_16x16x32_f16(afP[ks], b1, acc1, 0, 0, 0);
            }
        }
        #pragma unroll
        for (int r = 0; r < 4; ++r) { acc0[r] += cbv[0]; acc1[r] += cbv[1]; }

        // ---- partial LN stats over own 32 cols; publish (512 B) + sdone ----
        {
            float* pb = a.pstat + ((((size_t)(u * 4 + (t & 3)) * 2 + rh) * 16 + cs) * 64) * 2;
            #pragma unroll
            for (int r = 0; r < 4; ++r) {
                float s = acc0[r] + acc1[r];
                float q = __builtin_fmaf(acc0[r], acc0[r], acc1[r] * acc1[r]);
                s += __shfl_xor(s, 1); q += __shfl_xor(q, 1);
                s += __shfl_xor(s, 2); q += __shfl_xor(q, 2);
                s += __shfl_xor(s, 4); q += __shfl_xor(q, 4);
                s += __shfl_xor(s, 8); q += __shfl_xor(q, 8);
                if (r15 == 0) {
                    int row = w * 16 + quad * 4 + r;
                    st_ps(pb + row * 2, s, q);
                }
            }
        }
        __syncthreads();    // drain pstat stores
        if (tid == 0) st_flag_rel(&a.sdone[fl], t + 1);

        // ---- wait-2: all 16 col-peers' stats ----
        for (;;) {
            int ok = 1;
            if (tid < 16) ok = (ld_flag(&a.sdone[((u * 2 + rh) * 16 + tid) * FPAD]) >= t + 1);
            if (__syncthreads_and(ok)) break;
            __builtin_amdgcn_s_sleep(1);
        }
        asm volatile("" ::: "memory");

        // ---- finish stats: row = tid (64 rows) ----
        if (tid < 64) {
            const float* pb = a.pstat + (((size_t)(u * 4 + (t & 3)) * 2 + rh) * 16) * 128;
            float ss = 0.f, qq = 0.f;
            #pragma unroll
            for (int c = 0; c < 16; ++c) {
                float s, q;
                ld_ps(pb + (c * 64 + tid) * 2, s, q);
                ss += s; qq += q;
            }
            float m = ss * (1.0f / Hdim);
            float var = qq * (1.0f / Hdim) - m * m;
            float rstd = rsqrtf(var + 1e-5f);
            mr[tid][0] = rstd;
            mr[tid][1] = -m * rstd;
        }
        __syncthreads();

        // ---- tanh own slice -> per-wave LDS tile (swizzled) ----
        #pragma unroll
        for (int r = 0; r < 4; ++r) {
            int row = quad * 4 + r;
            int grow = w * 16 + row;
            float A = mr[grow][0], C = mr[grow][1];
            float x0 = __builtin_fmaf(__builtin_fmaf(acc0[r], A, C), g2[0], b2[0]);
            float x1 = __builtin_fmaf(__builtin_fmaf(acc1[r], A, C), g2[1], b2[1]);
            float E0 = __expf(x0), E1 = __expf(x1);
            int sw = (row >> 2) << 3;
            tile[w][row * 32 + ((r15) ^ sw)]      = (h16)(1.0f - __fdividef(2.0f, E0 + 1.0f));
            tile[w][row * 32 + ((16 + r15) ^ sw)] = (h16)(1.0f - __fdividef(2.0f, E1 + 1.0f));
        }
        // ---- pack A-frag (kf = cs, mt = w) + publish; h2 write (l==2) ----
        {
            int row = lane & 15;
            int cb2 = (quad * 8) ^ ((row >> 2) << 3);
            union { half8 v; uint uu[4]; } o;
            o.v = *(const half8*)&tile[w][row * 32 + cb2];
            st8c(a.hbuf + hb_idx(u, t & 3, rh, cs, w) + lane * 8, o.uu);
        }
        if (l == 2) {
            int row = lane >> 2, cg = (lane & 3) * 8;
            uint4 v = *(const uint4*)&tile[w][row * 32 + (cg ^ ((row >> 2) << 3))];
            int grow = rh * 64 + w * 16 + row;
            *(uint4*)&a.h2[(((size_t)dir * Tdim + t) * Bdim + grow) * Hdim + cs * 32 + cg] = v;
        }
        __syncthreads();    // drain hbuf stores
        if (tid == 0) st_flag_rel(&a.hdone[fl], t + 1);
    }
}

// ---------------- FC: logits = [h_l2r ; gather(h_r2l)] @ W_fc + b_fc -------------
__global__ __launch_bounds__(NTHR) void fc_kernel(
    const h16* __restrict__ h2, const int* __restrict__ pad,
    const float* __restrict__ Wfc, const float* __restrict__ bfc,
    float* __restrict__ out)
{
    __shared__ float sA[64 * 68];
    __shared__ float sB[64 * 48];
    const int blk = blockIdx.x, tid = threadIdx.x;
    const int b = blk >> 2;
    const int j0 = (blk & 3) * 64;
    const int p = pad[b];
    const int rg = tid >> 4;
    const int c0 = (tid & 15) * 3;
    float acc[4][3] = {};

    for (int k0 = 0; k0 < 2 * Hdim; k0 += 64) {
        {
            int rr = tid >> 2;
            int kp = (tid & 3) * 16;
            int j = j0 + rr;
            const h16* src;
            if (k0 < Hdim) {
                src = h2 + (((size_t)0 * Tdim + j) * Bdim + b) * Hdim + k0 + kp;
            } else {
                int idx = (j < p) ? (p - j - 1) : j;
                src = h2 + (((size_t)1 * Tdim + idx) * Bdim + b) * Hdim + (k0 - Hdim) + kp;
            }
            union { uint4 u4; h16 h[8]; } w0, w1;
            w0.u4 = *(const uint4*)src;
            w1.u4 = *(const uint4*)(src + 8);
            #pragma unroll
            for (int i = 0; i < 8; ++i) {
                sA[rr * 68 + kp + i]     = (float)w0.h[i];
                sA[rr * 68 + kp + 8 + i] = (float)w1.h[i];
            }
        }
        for (int e = tid; e < 64 * 48; e += NTHR) {
            int kk = e / 48, c = e - kk * 48;
            sB[e] = (c < NC) ? Wfc[(k0 + kk) * NC + c] : 0.f;
        }
        __syncthreads();
        for (int kk = 0; kk < 64; ++kk) {
            float b0 = sB[kk * 48 + c0 + 0];
            float b1 = sB[kk * 48 + c0 + 1];
            float b2 = sB[kk * 48 + c0 + 2];
            #pragma unroll
            for (int i = 0; i < 4; ++i) {
                float av = sA[(rg * 4 + i) * 68 + kk];
                acc[i][0] += av * b0; acc[i][1] += av * b1; acc[i][2] += av * b2;
            }
        }
        __syncthreads();
    }
    #pragma unroll
    for (int i = 0; i < 4; ++i) {
        int r = blk * 64 + rg * 4 + i;
        #pragma unroll
        for (int jj = 0; jj < 3; ++jj) {
            int c = c0 + jj;
            if (c < NC) out[r * NC + c] = acc[i][jj] + bfc[c];
        }
    }
}

extern "C" void kernel_launch(void* const* d_in, const int* in_sizes, int n_in,
                              void* d_out, int out_size, void* d_ws, size_t ws_size,
                              hipStream_t stream) {
    const float* x      = (const float*)d_in[0];
    const float* rx     = (const float*)d_in[1];
    const int*   pad    = (const int*)d_in[2];
    const float* Wemb   = (const float*)d_in[4];
    const float* bemb   = (const float*)d_in[5];
    const float* Wx_l2r = (const float*)d_in[6];
    const float* bx_l2r = (const float*)d_in[7];
    const float* Wh_l2r = (const float*)d_in[8];
    const float* bh_l2r = (const float*)d_in[9];
    const float* Wx_r2l = (const float*)d_in[10];
    const float* bx_r2l = (const float*)d_in[11];
    const float* Wh_r2l = (const float*)d_in[12];
    const float* bh_r2l = (const float*)d_in[13];
    const float* lng    = (const float*)d_in[14];
    const float* lnb    = (const float*)d_in[15];
    const float* Wfc    = (const float*)d_in[16];
    const float* bfc    = (const float*)d_in[17];

    char* base = (char*)d_ws;
    size_t off = 0;
    auto alloc = [&](size_t bytes) { char* p = base + off; off += (bytes + 255) & ~(size_t)255; return p; };
    h16*   zx0f  = (h16*)  alloc((size_t)2 * Tdim * 32 * 8 * 64 * 4 * 2);      // 67 MB
    h16*   h2    = (h16*)  alloc((size_t)2 * Tdim * Bdim * Hdim * 2);          // 67 MB
    h16*   Wfrag = (h16*)  alloc((size_t)6 * 16 * 32768 * 2);                  // 6.3 MB
    h16*   W0f   = (h16*)  alloc((size_t)2 * 32 * 10 * 64 * 8 * 2);            // 0.66 MB
    h16*   hbuf  = (h16*)  alloc((size_t)6 * 4 * 2 * 16 * 4 * 512 * 2);        // 3.1 MB
    float* pstat = (float*)alloc((size_t)6 * 4 * 2 * 16 * 64 * 2 * 4);         // 786 KB
    float* W0    = (float*)alloc((size_t)2 * KXdim * Hdim * 4);
    float* cb    = (float*)alloc((size_t)2 * 3 * Hdim * 4);
    int*   hdone = (int*)  alloc((size_t)192 * FPAD * 4);
    int*   sdone = (int*)  alloc((size_t)192 * FPAD * 4);

    prep1_kernel<<<(2 * KXdim * Hdim + 2 * 3 * Hdim) / NTHR, NTHR, 0, stream>>>(
        Wemb, bemb, Wx_l2r, bx_l2r, bh_l2r, Wx_r2l, bx_r2l, bh_r2l, W0, cb);

    pack_W_kernel<<<(6 * 16 * 32 * 2 * 64 * 8) / NTHR, NTHR, 0, stream>>>(
        W0, Wx_l2r, Wh_l2r, Wx_r2l, Wh_r2l, Wfrag);

    pack_W0f_kernel<<<(2 * 32 * 10 * 64 * 8) / NTHR, NTHR, 0, stream>>>(W0, W0f);

    zx0_kernel<<<1024, NTHR, 0, stream>>>(x, rx, W0f, cb, zx0f);

    zeroinit_kernel<<<(192 * FPAD + NTHR - 1) / NTHR, NTHR, 0, stream>>>(hdone, sdone);

    PipeArgs a;
    a.Wfrag = Wfrag; a.zx0f = zx0f; a.cb = cb; a.lng = lng; a.lnb = lnb;
    a.hbuf = hbuf; a.pstat = pstat; a.h2 = h2;
    a.hdone = hdone; a.sdone = sdone;
    void* kargs[] = { &a };
    hipLaunchCooperativeKernel((void*)rnn_pipe, dim3(192), dim3(NTHR), kargs, 0, stream);

    fc_kernel<<<(Bdim * Tdim) / 64, NTHR, 0, stream>>>(h2, pad, Wfc, bfc, (float*)d_out);
}

// Round 8
// 3734.495 us; speedup vs baseline: 5.2461x; 1.1396x over previous
//
#include <hip/hip_runtime.h>

#define Bdim 128
#define Tdim 256
#define Hdim 512
#define INdim 300
#define KXdim 320
#define NC 45
#define NTHR 256
#define FPAD 16   // ints per flag (64B cache line padding)

typedef _Float16 h16;
typedef __attribute__((ext_vector_type(8))) _Float16 half8;
typedef __attribute__((ext_vector_type(4))) float float4v;
typedef __attribute__((ext_vector_type(2))) float float2v;
typedef __attribute__((ext_vector_type(4))) uint uint4v;
typedef unsigned long long u64;

// ---- flag helpers: agent-scope atomics (4B, single line) ----
__device__ __forceinline__ int ld_flag(const int* p) {
    return __hip_atomic_load((int*)p, __ATOMIC_RELAXED, __HIP_MEMORY_SCOPE_AGENT);
}
__device__ __forceinline__ void st_flag_rel(int* p, int v) {
    __hip_atomic_store(p, v, __ATOMIC_RELEASE, __HIP_MEMORY_SCOPE_AGENT);
}

// ---- WIDE coherent data path: 16B dwordx4 with sc0 sc1 (L1/L2-bypass, LLC
// coherent) — same coherence as agent atomics but coalesced, 4x fewer
// transactions, no 4B->sector write amplification (R7: WRITE_SIZE 953MB vs
// 260MB payload). Loads are issue-only; drain with WAIT_VM() before use.
#define WAIT_VM() do { \
    asm volatile("s_waitcnt vmcnt(0)" ::: "memory"); \
    __builtin_amdgcn_sched_barrier(0); \
} while (0)

__device__ __forceinline__ half8 ld16v(const h16* p) {
    half8 r;
    asm volatile("global_load_dwordx4 %0, %1, off sc0 sc1"
                 : "=&v"(r) : "v"(p) : "memory");
    return r;
}
__device__ __forceinline__ float2v ld8vf(const float* p) {
    float2v r;
    asm volatile("global_load_dwordx2 %0, %1, off sc0 sc1"
                 : "=&v"(r) : "v"(p) : "memory");
    return r;
}
__device__ __forceinline__ void st16v(h16* p, half8 v) {
    asm volatile("global_store_dwordx4 %0, %1, off sc0 sc1"
                 :: "v"(p), "v"(v) : "memory");
}
__device__ __forceinline__ void st16vf(float* p, uint4v v) {
    asm volatile("global_store_dwordx4 %0, %1, off sc0 sc1"
                 :: "v"(p), "v"(v) : "memory");
}

// ---------------- prep1: W0 = Wemb @ Wx0 (fp32), cb fused biases ----------------
__global__ __launch_bounds__(NTHR) void prep1_kernel(
    const float* Wemb, const float* bemb,
    const float* Wx_l2r, const float* bx_l2r, const float* bh_l2r,
    const float* Wx_r2l, const float* bx_r2l, const float* bh_r2l,
    float* W0, float* cb)
{
    int gid = blockIdx.x * NTHR + threadIdx.x;
    const int nW0 = 2 * KXdim * Hdim;
    if (gid < nW0) {
        int dir = gid / (KXdim * Hdim);
        int rem = gid % (KXdim * Hdim);
        int i = rem / Hdim, h = rem % Hdim;
        const float* Wx = dir ? Wx_r2l : Wx_l2r;
        float s = 0.f;
        if (i < INdim) {
            for (int k = 0; k < Hdim; ++k)
                s += Wemb[i * Hdim + k] * Wx[k * Hdim + h];
        }
        W0[gid] = s;
    } else {
        int idx = gid - nW0;
        if (idx < 2 * 3 * Hdim) {
            int dir = idx / (3 * Hdim);
            int l = (idx / Hdim) % 3;
            int h = idx % Hdim;
            const float* Wx = dir ? Wx_r2l : Wx_l2r;
            const float* bx = dir ? bx_r2l : bx_l2r;
            const float* bh = dir ? bh_r2l : bh_l2r;
            float s = bx[l * Hdim + h] + bh[l * Hdim + h];
            if (l == 0) {
                for (int k = 0; k < Hdim; ++k)
                    s += bemb[k] * Wx[k * Hdim + h];
            }
            cb[idx] = s;
        }
    }
}

// ---------------- pack_W: fp16 B-frag layout [u][cs16][ks32][nt2][lane64][j8] ----
__global__ __launch_bounds__(NTHR) void pack_W_kernel(
    const float* W0,
    const float* Wx_l2r, const float* Wh_l2r,
    const float* Wx_r2l, const float* Wh_r2l,
    h16* Wfrag)
{
    int e = blockIdx.x * NTHR + threadIdx.x;
    if (e >= 6 * 16 * 32 * 2 * 64 * 8) return;
    int j    = e & 7;
    int lane = (e >> 3) & 63;
    int nt   = (e >> 9) & 1;
    int ks   = (e >> 10) & 31;
    int cs   = (e >> 15) & 15;
    int u    = e >> 19;
    int dir = u / 3, l = u % 3;
    int n  = cs * 32 + nt * 16 + (lane & 15);
    int kk = ks * 32 + ((lane >> 4) * 8) + j;
    float v;
    if (kk < 512) {
        if (l == 0) {
            v = (kk < KXdim) ? W0[(dir * KXdim + kk) * Hdim + n] : 0.f;
        } else {
            const float* Wx = dir ? Wx_r2l : Wx_l2r;
            v = Wx[(l * Hdim + kk) * Hdim + n];
        }
    } else {
        const float* Wh = dir ? Wh_r2l : Wh_l2r;
        v = Wh[(l * Hdim + (kk - 512)) * Hdim + n];
    }
    Wfrag[e] = (h16)v;
}

// ---------------- pack_W0f: fp16 B-frags of W0 for zx0 kernel --------------------
__global__ __launch_bounds__(NTHR) void pack_W0f_kernel(const float* W0, h16* W0f)
{
    int e = blockIdx.x * NTHR + threadIdx.x;
    if (e >= 2 * 32 * 10 * 64 * 8) return;
    int j    = e & 7;
    int lane = (e >> 3) & 63;
    int rest = e >> 9;
    int ks   = rest % 10;
    rest /= 10;
    int nt   = rest & 31;
    int dir  = rest >> 5;
    int k = ks * 32 + ((lane >> 4) * 8) + j;
    int n = nt * 16 + (lane & 15);
    W0f[e] = (h16)W0[(dir * KXdim + k) * Hdim + n];
}

// ---------------- zx0: zx0f[dir][t][nt32][mt8][lane64][reg4] fp16 ----------------
__global__ __launch_bounds__(NTHR) void zx0_kernel(
    const float* __restrict__ x0, const float* __restrict__ x1,
    const h16* __restrict__ W0f, const float* __restrict__ cb,
    h16* __restrict__ zx0f)
{
    int bx = blockIdx.x;
    int t = bx & 255, mh = (bx >> 8) & 1, dir = bx >> 9;
    const int tid = threadIdx.x;
    __shared__ h16 xl[64 * 328];
    const float* xs = dir ? x1 : x0;
    for (int i = tid; i < 64 * 328; i += NTHR) {
        int r = i / 328, k = i - r * 328;
        int b = mh * 64 + r;
        float v = (k < INdim) ? xs[(b * Tdim + t) * INdim + k] : 0.f;
        xl[i] = (h16)v;
    }
    __syncthreads();
    int wave = tid >> 6, lane = tid & 63;
    int r15 = lane & 15, q = lane >> 4;
    for (int nt = 0; nt < 32; ++nt) {
        float4v acc = {0.f, 0.f, 0.f, 0.f};
        #pragma unroll
        for (int ks = 0; ks < 10; ++ks) {
            half8 af = *(const half8*)&xl[(wave * 16 + r15) * 328 + ks * 32 + q * 8];
            half8 bf = *(const half8*)&W0f[(((dir * 32 + nt) * 10 + ks) * 64 + lane) * 8];
            acc = __builtin_amdgcn_mfma_f32_16x16x32_f16(af, bf, acc, 0, 0, 0);
        }
        int col = nt * 16 + r15;
        float cbv = cb[(dir * 3 + 0) * Hdim + col];
        union { h16 h[4]; uint2 u2; } o;
        #pragma unroll
        for (int r = 0; r < 4; ++r) o.h[r] = (h16)(acc[r] + cbv);
        h16* dst = zx0f + (((( (size_t)dir * Tdim + t) * 32 + nt) * 8 + (mh * 4 + wave)) * 64 + lane) * 4;
        *(uint2*)dst = o.u2;
    }
}

// ---------------- zeroinit: flags ------------------------------------------------
__global__ __launch_bounds__(NTHR) void zeroinit_kernel(int* hdone, int* sdone)
{
    int gid = blockIdx.x * NTHR + threadIdx.x;
    if (gid < 192 * FPAD) { hdone[gid] = 0; sdone[gid] = 0; }
}

// ---------------- main persistent pipeline kernel --------------------------------
// R7 structure: 192 blocks = 6 units x 2 row-halves x 16 col-slices; weight
// slice LDS-resident (loaded once); 2 small LLC exchanges/step. R8: all
// cross-block data moves via 16B sc0sc1 dwordx4 (see helpers above).
struct PipeArgs {
    const h16* Wfrag;    // [6][cs16][ks32][nt2][64][8]
    const h16* zx0f;     // [2][T][nt32][mt8][64][4] fp16
    const float* cb;     // [2][3][H]
    const float* lng;    // [3][H]
    const float* lnb;    // [3][H]
    h16* hbuf;           // [6][slot4][rh2][kf16][mt4][64][8] post-tanh h A-frags
    float* pstat;        // [6][slot4][rh2][cs16][row64][2]  (s, q) pairs
    h16* h2;             // [2][T][B][H]
    int* hdone;          // [6][2][16] * FPAD
    int* sdone;          // [6][2][16] * FPAD
};

__device__ __forceinline__ size_t hb_idx(int u, int slot, int rh, int kf, int mt) {
    return ((((size_t)(u * 4 + slot) * 2 + rh) * 16 + kf) * 4 + mt) * 512;
}

__global__ __launch_bounds__(NTHR, 2) void rnn_pipe(PipeArgs a)
{
    const int blk = blockIdx.x, tid = threadIdx.x;
    const int w = tid >> 6, lane = tid & 63;
    const int r15 = lane & 15, quad = lane >> 4;
    const int u = blk >> 5, rh = (blk >> 4) & 1, cs = blk & 15;
    const int dir = u / 3, l = u % 3;

    __shared__ h16 wlds[32768];      // 64 KB: fused W slice [ks32][nt2][64][8]
    __shared__ h16 tile[4][512];     // 4 KB: per-wave 16x32 transpose tiles
    __shared__ float mr[64][2];      // rstd, -m*rstd per row

    {   // stage weight slice once (straight 64 KB copy of Wfrag[u][cs])
        const h16* wsrc = a.Wfrag + (size_t)(u * 16 + cs) * 32768;
        for (int i = tid * 8; i < 32768; i += NTHR * 8)
            *(uint4*)&wlds[i] = *(const uint4*)&wsrc[i];
    }
    // per-lane LN/bias constants (cols cs*32 + n*16 + r15)
    float g2[2], b2[2], cbv[2];
    #pragma unroll
    for (int n = 0; n < 2; ++n) {
        int col = cs * 32 + n * 16 + r15;
        g2[n] = 2.0f * a.lng[l * Hdim + col];
        b2[n] = 2.0f * a.lnb[l * Hdim + col];
        cbv[n] = (l > 0) ? a.cb[(dir * 3 + l) * Hdim + col] : 0.f;   // l0: baked in zx0f
    }
    __syncthreads();

    const int fl = ((u * 2 + rh) * 16 + cs) * FPAD;
    const int gmt = rh * 4 + w;   // global m-tile for zx0f

    for (int t = 0; t < Tdim; ++t) {
        // ---- wait-1: own peers h(t-1); lower h(t); upper-throttle h(t-4) freed ----
        for (;;) {
            int ok = 1;
            if (tid < 16) {
                if (t > 0) ok = (ld_flag(&a.hdone[((u * 2 + rh) * 16 + tid) * FPAD]) >= t);
            } else if (tid >= 64 && tid < 80) {
                if (l > 0) ok = (ld_flag(&a.hdone[(((u - 1) * 2 + rh) * 16 + (tid - 64)) * FPAD]) >= t + 1);
            } else if (tid >= 128 && tid < 144) {
                if (l < 2 && t >= 4) ok = (ld_flag(&a.hdone[(((u + 1) * 2 + rh) * 16 + (tid - 128)) * FPAD]) >= t - 3);
            }
            if (__syncthreads_and(ok)) break;
            __builtin_amdgcn_s_sleep(1);
        }
        asm volatile("" ::: "memory");

        // ---- accumulator init ----
        float4v acc0, acc1;
        if (l == 0) {
            const h16* zp = a.zx0f +
                ((((size_t)dir * Tdim + t) * 32 + cs * 2) * 8 + gmt) * 256 + lane * 4;
            union { uint2 uu; h16 hh[4]; } v0, v1;
            v0.uu = *(const uint2*)zp;
            v1.uu = *(const uint2*)(zp + 2048);
            #pragma unroll
            for (int r = 0; r < 4; ++r) { acc0[r] = (float)v0.hh[r]; acc1[r] = (float)v1.hh[r]; }
        } else {
            acc0 = (float4v){0.f, 0.f, 0.f, 0.f};
            acc1 = (float4v){0.f, 0.f, 0.f, 0.f};
        }

        // ---- batch A-frag loads (16B coherent, one drain), then MFMAs ----
        half8 afL[16], afP[16];
        if (l > 0) {
            const h16* hbL = a.hbuf + hb_idx(u - 1, t & 3, rh, 0, w) + lane * 8;
            #pragma unroll
            for (int ks = 0; ks < 16; ++ks)
                afL[ks] = ld16v(hbL + (size_t)ks * 2048);
        }
        if (t > 0) {
            const h16* hbP = a.hbuf + hb_idx(u, (t + 3) & 3, rh, 0, w) + lane * 8;
            #pragma unroll
            for (int ks = 0; ks < 16; ++ks)
                afP[ks] = ld16v(hbP + (size_t)ks * 2048);
        }
        WAIT_VM();
        if (l > 0) {
            #pragma unroll
            for (int ks = 0; ks < 16; ++ks) {
                half8 b0 = *(const half8*)&wlds[((ks * 2 + 0) * 64 + lane) * 8];
                half8 b1 = *(const half8*)&wlds[((ks * 2 + 1) * 64 + lane) * 8];
                acc0 = __builtin_amdgcn_mfma_f32_16x16x32_f16(afL[ks], b0, acc0, 0, 0, 0);
                acc1 = __builtin_amdgcn_mfma_f32_16x16x32_f16(afL[ks], b1, acc1, 0, 0, 0);
            }
        }
        if (t > 0) {
            #pragma unroll
            for (int ks = 0; ks < 16; ++ks) {
                half8 b0 = *(const half8*)&wlds[(((ks + 16) * 2 + 0) * 64 + lane) * 8];
                half8 b1 = *(const half8*)&wlds[(((ks + 16) * 2 + 1) * 64 + lane) * 8];
                acc0 = __builtin_amdgcn_mfma_f32_16x16x32_f16(afP[ks], b0, acc0, 0, 0, 0);
                acc1 = __builtin_amdgcn_mfma_f32_16x16x32_f16(afP[ks], b1, acc1, 0, 0, 0);
            }
        }
        #pragma unroll
        for (int r = 0; r < 4; ++r) { acc0[r] += cbv[0]; acc1[r] += cbv[1]; }

        // ---- partial LN stats over own 32 cols; publish (2x16B/lane) + sdone ----
        {
            float sr[4], qr[4];
            #pragma unroll
            for (int r = 0; r < 4; ++r) {
                float s = acc0[r] + acc1[r];
                float q = __builtin_fmaf(acc0[r], acc0[r], acc1[r] * acc1[r]);
                s += __shfl_xor(s, 1); q += __shfl_xor(q, 1);
                s += __shfl_xor(s, 2); q += __shfl_xor(q, 2);
                s += __shfl_xor(s, 4); q += __shfl_xor(q, 4);
                s += __shfl_xor(s, 8); q += __shfl_xor(q, 8);
                sr[r] = s; qr[r] = q;
            }
            if (r15 == 0) {
                float* pb = a.pstat + ((((size_t)(u * 4 + (t & 3)) * 2 + rh) * 16 + cs) * 64) * 2
                          + (w * 16 + quad * 4) * 2;
                union { float f[4]; uint4v u; } v1, v2;
                v1.f[0] = sr[0]; v1.f[1] = qr[0]; v1.f[2] = sr[1]; v1.f[3] = qr[1];
                v2.f[0] = sr[2]; v2.f[1] = qr[2]; v2.f[2] = sr[3]; v2.f[3] = qr[3];
                st16vf(pb, v1.u);
                st16vf(pb + 4, v2.u);
            }
        }
        asm volatile("s_waitcnt vmcnt(0)" ::: "memory");   // drain pstat stores
        __syncthreads();
        if (tid == 0) st_flag_rel(&a.sdone[fl], t + 1);

        // ---- wait-2: all 16 col-peers' stats ----
        for (;;) {
            int ok = 1;
            if (tid < 16) ok = (ld_flag(&a.sdone[((u * 2 + rh) * 16 + tid) * FPAD]) >= t + 1);
            if (__syncthreads_and(ok)) break;
            __builtin_amdgcn_s_sleep(1);
        }
        asm volatile("" ::: "memory");

        // ---- finish stats: row = tid (64 rows), batched 8B coherent loads ----
        if (tid < 64) {
            const float* pb = a.pstat + (((size_t)(u * 4 + (t & 3)) * 2 + rh) * 16) * 128;
            float2v pv[16];
            #pragma unroll
            for (int c = 0; c < 16; ++c)
                pv[c] = ld8vf(pb + (c * 64 + tid) * 2);
            WAIT_VM();
            float ss = 0.f, qq = 0.f;
            #pragma unroll
            for (int c = 0; c < 16; ++c) { ss += pv[c][0]; qq += pv[c][1]; }
            float m = ss * (1.0f / Hdim);
            float var = qq * (1.0f / Hdim) - m * m;
            float rstd = rsqrtf(var + 1e-5f);
            mr[tid][0] = rstd;
            mr[tid][1] = -m * rstd;
        }
        __syncthreads();

        // ---- tanh own slice -> per-wave LDS tile (swizzled) ----
        #pragma unroll
        for (int r = 0; r < 4; ++r) {
            int row = quad * 4 + r;
            int grow = w * 16 + row;
            float A = mr[grow][0], C = mr[grow][1];
            float x0 = __builtin_fmaf(__builtin_fmaf(acc0[r], A, C), g2[0], b2[0]);
            float x1 = __builtin_fmaf(__builtin_fmaf(acc1[r], A, C), g2[1], b2[1]);
            float E0 = __expf(x0), E1 = __expf(x1);
            int sw = (row >> 2) << 3;
            tile[w][row * 32 + ((r15) ^ sw)]      = (h16)(1.0f - __fdividef(2.0f, E0 + 1.0f));
            tile[w][row * 32 + ((16 + r15) ^ sw)] = (h16)(1.0f - __fdividef(2.0f, E1 + 1.0f));
        }
        // ---- pack A-frag (kf = cs, mt = w) + publish; h2 write (l==2) ----
        {
            int row = lane & 15;
            int cb2 = (quad * 8) ^ ((row >> 2) << 3);
            half8 v = *(const half8*)&tile[w][row * 32 + cb2];
            st16v(a.hbuf + hb_idx(u, t & 3, rh, cs, w) + lane * 8, v);
        }
        if (l == 2) {
            int row = lane >> 2, cg = (lane & 3) * 8;
            uint4 v = *(const uint4*)&tile[w][row * 32 + (cg ^ ((row >> 2) << 3))];
            int grow = rh * 64 + w * 16 + row;
            *(uint4*)&a.h2[(((size_t)dir * Tdim + t) * Bdim + grow) * Hdim + cs * 32 + cg] = v;
        }
        asm volatile("s_waitcnt vmcnt(0)" ::: "memory");   // drain hbuf stores
        __syncthreads();
        if (tid == 0) st_flag_rel(&a.hdone[fl], t + 1);
    }
}

// ---------------- FC: logits = [h_l2r ; gather(h_r2l)] @ W_fc + b_fc -------------
__global__ __launch_bounds__(NTHR) void fc_kernel(
    const h16* __restrict__ h2, const int* __restrict__ pad,
    const float* __restrict__ Wfc, const float* __restrict__ bfc,
    float* __restrict__ out)
{
    __shared__ float sA[64 * 68];
    __shared__ float sB[64 * 48];
    const int blk = blockIdx.x, tid = threadIdx.x;
    const int b = blk >> 2;
    const int j0 = (blk & 3) * 64;
    const int p = pad[b];
    const int rg = tid >> 4;
    const int c0 = (tid & 15) * 3;
    float acc[4][3] = {};

    for (int k0 = 0; k0 < 2 * Hdim; k0 += 64) {
        {
            int rr = tid >> 2;
            int kp = (tid & 3) * 16;
            int j = j0 + rr;
            const h16* src;
            if (k0 < Hdim) {
                src = h2 + (((size_t)0 * Tdim + j) * Bdim + b) * Hdim + k0 + kp;
            } else {
                int idx = (j < p) ? (p - j - 1) : j;
                src = h2 + (((size_t)1 * Tdim + idx) * Bdim + b) * Hdim + (k0 - Hdim) + kp;
            }
            union { uint4 u4; h16 h[8]; } w0, w1;
            w0.u4 = *(const uint4*)src;
            w1.u4 = *(const uint4*)(src + 8);
            #pragma unroll
            for (int i = 0; i < 8; ++i) {
                sA[rr * 68 + kp + i]     = (float)w0.h[i];
                sA[rr * 68 + kp + 8 + i] = (float)w1.h[i];
            }
        }
        for (int e = tid; e < 64 * 48; e += NTHR) {
            int kk = e / 48, c = e - kk * 48;
            sB[e] = (c < NC) ? Wfc[(k0 + kk) * NC + c] : 0.f;
        }
        __syncthreads();
        for (int kk = 0; kk < 64; ++kk) {
            float b0 = sB[kk * 48 + c0 + 0];
            float b1 = sB[kk * 48 + c0 + 1];
            float b2 = sB[kk * 48 + c0 + 2];
            #pragma unroll
            for (int i = 0; i < 4; ++i) {
                float av = sA[(rg * 4 + i) * 68 + kk];
                acc[i][0] += av * b0; acc[i][1] += av * b1; acc[i][2] += av * b2;
            }
        }
        __syncthreads();
    }
    #pragma unroll
    for (int i = 0; i < 4; ++i) {
        int r = blk * 64 + rg * 4 + i;
        #pragma unroll
        for (int jj = 0; jj < 3; ++jj) {
            int c = c0 + jj;
            if (c < NC) out[r * NC + c] = acc[i][jj] + bfc[c];
        }
    }
}

extern "C" void kernel_launch(void* const* d_in, const int* in_sizes, int n_in,
                              void* d_out, int out_size, void* d_ws, size_t ws_size,
                              hipStream_t stream) {
    const float* x      = (const float*)d_in[0];
    const float* rx     = (const float*)d_in[1];
    const int*   pad    = (const int*)d_in[2];
    const float* Wemb   = (const float*)d_in[4];
    const float* bemb   = (const float*)d_in[5];
    const float* Wx_l2r = (const float*)d_in[6];
    const float* bx_l2r = (const float*)d_in[7];
    const float* Wh_l2r = (const float*)d_in[8];
    const float* bh_l2r = (const float*)d_in[9];
    const float* Wx_r2l = (const float*)d_in[10];
    const float* bx_r2l = (const float*)d_in[11];
    const float* Wh_r2l = (const float*)d_in[12];
    const float* bh_r2l = (const float*)d_in[13];
    const float* lng    = (const float*)d_in[14];
    const float* lnb    = (const float*)d_in[15];
    const float* Wfc    = (const float*)d_in[16];
    const float* bfc    = (const float*)d_in[17];

    char* base = (char*)d_ws;
    size_t off = 0;
    auto alloc = [&](size_t bytes) { char* p = base + off; off += (bytes + 255) & ~(size_t)255; return p; };
    h16*   zx0f  = (h16*)  alloc((size_t)2 * Tdim * 32 * 8 * 64 * 4 * 2);      // 67 MB
    h16*   h2    = (h16*)  alloc((size_t)2 * Tdim * Bdim * Hdim * 2);          // 67 MB
    h16*   Wfrag = (h16*)  alloc((size_t)6 * 16 * 32768 * 2);                  // 6.3 MB
    h16*   W0f   = (h16*)  alloc((size_t)2 * 32 * 10 * 64 * 8 * 2);            // 0.66 MB
    h16*   hbuf  = (h16*)  alloc((size_t)6 * 4 * 2 * 16 * 4 * 512 * 2);        // 3.1 MB
    float* pstat = (float*)alloc((size_t)6 * 4 * 2 * 16 * 64 * 2 * 4);         // 786 KB
    float* W0    = (float*)alloc((size_t)2 * KXdim * Hdim * 4);
    float* cb    = (float*)alloc((size_t)2 * 3 * Hdim * 4);
    int*   hdone = (int*)  alloc((size_t)192 * FPAD * 4);
    int*   sdone = (int*)  alloc((size_t)192 * FPAD * 4);

    prep1_kernel<<<(2 * KXdim * Hdim + 2 * 3 * Hdim) / NTHR, NTHR, 0, stream>>>(
        Wemb, bemb, Wx_l2r, bx_l2r, bh_l2r, Wx_r2l, bx_r2l, bh_r2l, W0, cb);

    pack_W_kernel<<<(6 * 16 * 32 * 2 * 64 * 8) / NTHR, NTHR, 0, stream>>>(
        W0, Wx_l2r, Wh_l2r, Wx_r2l, Wh_r2l, Wfrag);

    pack_W0f_kernel<<<(2 * 32 * 10 * 64 * 8) / NTHR, NTHR, 0, stream>>>(W0, W0f);

    zx0_kernel<<<1024, NTHR, 0, stream>>>(x, rx, W0f, cb, zx0f);

    zeroinit_kernel<<<(192 * FPAD + NTHR - 1) / NTHR, NTHR, 0, stream>>>(hdone, sdone);

    PipeArgs a;
    a.Wfrag = Wfrag; a.zx0f = zx0f; a.cb = cb; a.lng = lng; a.lnb = lnb;
    a.hbuf = hbuf; a.pstat = pstat; a.h2 = h2;
    a.hdone = hdone; a.sdone = sdone;
    void* kargs[] = { &a };
    hipLaunchCooperativeKernel((void*)rnn_pipe, dim3(192), dim3(NTHR), kargs, 0, stream);

    fc_kernel<<<(Bdim * Tdim) / 64, NTHR, 0, stream>>>(h2, pad, Wfc, bfc, (float*)d_out);
}